// Round 1
// baseline (24084.195 us; speedup 1.0000x reference)
//
#include <hip/hip_runtime.h>
#include <cstdint>
#include <cstddef>

#define GXd 480
#define GYd 360
#define NBd 2
#define GXY (480*360)
#define EPSBN 1e-5f

// ---------- order-preserving float <-> uint map (for atomic max) ----------
__device__ __forceinline__ unsigned mapf(float f){
    unsigned u = __float_as_uint(f);
    return (u & 0x80000000u) ? ~u : (u | 0x80000000u);
}
__device__ __forceinline__ float unmapf(unsigned m){
    return (m & 0x80000000u) ? __uint_as_float(m ^ 0x80000000u)
                             : __uint_as_float(~m);
}

// ---------- dense layer helpers (fully unrolled, register-resident) ----------
template<int DIN, int DOUT>
__device__ __forceinline__ void dense(const float (&in)[DIN], float (&out)[DOUT],
                                      const float* __restrict__ w,
                                      const float* __restrict__ b){
#pragma unroll
    for (int j = 0; j < DOUT; j++) out[j] = b[j];
#pragma unroll
    for (int d = 0; d < DIN; d++){
        float v = in[d];
#pragma unroll
        for (int j = 0; j < DOUT; j++) out[j] = fmaf(v, w[d*DOUT + j], out[j]);
    }
}

template<int D>
__device__ __forceinline__ void bnrelu(float (&h)[D],
                                       const float* __restrict__ a,
                                       const float* __restrict__ c){
#pragma unroll
    for (int j = 0; j < D; j++) h[j] = fmaxf(fmaf(h[j], a[j], c[j]), 0.f);
}

// ---------- block-level sum/sumsq reduction of a per-thread register array ----------
template<int D>
__device__ __forceinline__ void reduce_stats(float (&h)[D], bool valid,
                                             float* __restrict__ gsum,
                                             float* __restrict__ gsq){
    __shared__ float ssum[D];
    __shared__ float ssq[D];
    int tid = threadIdx.x;
    for (int t = tid; t < D; t += 256){ ssum[t] = 0.f; ssq[t] = 0.f; }
    __syncthreads();
#pragma unroll
    for (int j = 0; j < D; j++){
        float v = valid ? h[j] : 0.f;
        float s = v * v;
#pragma unroll
        for (int o = 32; o > 0; o >>= 1){
            v += __shfl_down(v, o, 64);
            s += __shfl_down(s, o, 64);
        }
        if ((tid & 63) == 0){
            atomicAdd(&ssum[j], v);
            atomicAdd(&ssq[j], s);
        }
    }
    __syncthreads();
    for (int t = tid; t < D; t += 256){
        atomicAdd(&gsum[t], ssum[t]);
        atomicAdd(&gsq[t], ssq[t]);
    }
}

// ---------- stat pass kernels ----------
__global__ __launch_bounds__(256)
void k_stats0(const float* __restrict__ fea, float* gsum, float* gsq, int n){
    int i = blockIdx.x*256 + threadIdx.x;
    bool valid = i < n;
    int i2 = valid ? i : 0;
    float x[9];
#pragma unroll
    for (int d = 0; d < 9; d++) x[d] = fea[(size_t)i2*11 + d];
    reduce_stats<9>(x, valid, gsum, gsq);
}

__global__ __launch_bounds__(256)
void k_stats1(const float* __restrict__ fea,
              const float* __restrict__ w1, const float* __restrict__ b1,
              const float* __restrict__ a0, const float* __restrict__ c0,
              float* gsum, float* gsq, int n){
    int i = blockIdx.x*256 + threadIdx.x;
    bool valid = i < n;
    int i2 = valid ? i : 0;
    float x[9];
#pragma unroll
    for (int d = 0; d < 9; d++) x[d] = fmaf(fea[(size_t)i2*11 + d], a0[d], c0[d]);
    float h1[32];
    dense<9,32>(x, h1, w1, b1);
    reduce_stats<32>(h1, valid, gsum, gsq);
}

__global__ __launch_bounds__(256)
void k_stats2(const float* __restrict__ fea,
              const float* __restrict__ w1, const float* __restrict__ b1,
              const float* __restrict__ w2, const float* __restrict__ b2,
              const float* __restrict__ a0, const float* __restrict__ c0,
              const float* __restrict__ a1, const float* __restrict__ c1,
              float* gsum, float* gsq, int n){
    int i = blockIdx.x*256 + threadIdx.x;
    bool valid = i < n;
    int i2 = valid ? i : 0;
    float x[9];
#pragma unroll
    for (int d = 0; d < 9; d++) x[d] = fmaf(fea[(size_t)i2*11 + d], a0[d], c0[d]);
    float h1[32];
    dense<9,32>(x, h1, w1, b1);
    bnrelu<32>(h1, a1, c1);
    float h2[64];
    dense<32,64>(h1, h2, w2, b2);
    reduce_stats<64>(h2, valid, gsum, gsq);
}

__global__ __launch_bounds__(256)
void k_stats3(const float* __restrict__ fea,
              const float* __restrict__ w1, const float* __restrict__ b1,
              const float* __restrict__ w2, const float* __restrict__ b2,
              const float* __restrict__ w3, const float* __restrict__ b3,
              const float* __restrict__ a0, const float* __restrict__ c0,
              const float* __restrict__ a1, const float* __restrict__ c1,
              const float* __restrict__ a2, const float* __restrict__ c2,
              float* gsum, float* gsq, int n){
    int i = blockIdx.x*256 + threadIdx.x;
    bool valid = i < n;
    int i2 = valid ? i : 0;
    float x[9];
#pragma unroll
    for (int d = 0; d < 9; d++) x[d] = fmaf(fea[(size_t)i2*11 + d], a0[d], c0[d]);
    float h1[32];
    dense<9,32>(x, h1, w1, b1);
    bnrelu<32>(h1, a1, c1);
    float h2[64];
    dense<32,64>(h1, h2, w2, b2);
    bnrelu<64>(h2, a2, c2);
    float h3[128];
    dense<64,128>(h2, h3, w3, b3);
    reduce_stats<128>(h3, valid, gsum, gsq);
}

// ---------- finalize BN: a = g*rsqrt(var+eps); c = b - mu*a ----------
__global__ void k_fin(const float* __restrict__ sum, const float* __restrict__ sq,
                      const float* __restrict__ g, const float* __restrict__ bb,
                      float* __restrict__ a_out, float* __restrict__ c_out,
                      int D, float invN){
    int t = threadIdx.x;
    if (t < D){
        float mu  = sum[t] * invN;
        float var = fmaf(-mu, mu, sq[t] * invN);
        float rs  = rsqrtf(var + EPSBN);
        float a   = rs * g[t];
        a_out[t] = a;
        c_out[t] = fmaf(-mu, a, bb[t]);
    }
}

// ---------- full forward + scatter-max ----------
__global__ __launch_bounds__(256)
void k_scatter(const float* __restrict__ fea, const int* __restrict__ ind,
               const float* __restrict__ w1, const float* __restrict__ b1,
               const float* __restrict__ w2, const float* __restrict__ b2,
               const float* __restrict__ w3, const float* __restrict__ b3,
               const float* __restrict__ w4, const float* __restrict__ b4,
               const float* __restrict__ a0, const float* __restrict__ c0,
               const float* __restrict__ a1, const float* __restrict__ c1,
               const float* __restrict__ a2, const float* __restrict__ c2,
               const float* __restrict__ a3, const float* __restrict__ c3,
               unsigned* __restrict__ pooled, unsigned* __restrict__ pres,
               int n){
    int i = blockIdx.x*256 + threadIdx.x;
    bool valid = i < n;
    int i2 = valid ? i : 0;

    float x[9];
#pragma unroll
    for (int d = 0; d < 9; d++) x[d] = fmaf(fea[(size_t)i2*11 + d], a0[d], c0[d]);
    float h1[32];
    dense<9,32>(x, h1, w1, b1);
    bnrelu<32>(h1, a1, c1);
    float h2[64];
    dense<32,64>(h1, h2, w2, b2);
    bnrelu<64>(h2, a2, c2);
    float h3[128];
    dense<64,128>(h2, h3, w3, b3);
    bnrelu<128>(h3, a3, c3);

    int bb = ind[(size_t)i2*3 + 0];
    int gx = ind[(size_t)i2*3 + 1];
    int gy = ind[(size_t)i2*3 + 2];
    size_t spatial = (size_t)gx*GYd + gy;
    size_t pbase   = (size_t)bb*256*GXY + spatial;

    // layer 4 in chunks of 32 channels to cap register pressure
    for (int cb = 0; cb < 256; cb += 32){
        float acc[32];
#pragma unroll
        for (int cc = 0; cc < 32; cc++) acc[cc] = b4[cb + cc];
#pragma unroll
        for (int k = 0; k < 128; k++){
            float v = h3[k];
#pragma unroll
            for (int cc = 0; cc < 32; cc++)
                acc[cc] = fmaf(v, w4[k*256 + cb + cc], acc[cc]);
        }
        if (valid){
#pragma unroll
            for (int cc = 0; cc < 32; cc++)
                atomicMax(pooled + pbase + (size_t)(cb + cc)*GXY, mapf(acc[cc]));
        }
    }

    if (valid){
        float r0 = fea[(size_t)i2*11 + 9];
        float r1 = fea[(size_t)i2*11 + 10];
        size_t rbase = (size_t)bb*2*GXY + spatial;
        atomicMax(pres + rbase,        mapf(r0));
        atomicMax(pres + rbase + GXY,  mapf(r1));
    }
}

// ---------- 3x3 maxpool (pad -inf) + unmap; empty cell == 0.0 ----------
__global__ __launch_bounds__(256)
void k_maxpool(const unsigned* __restrict__ pooled, float* __restrict__ out){
    int gy = (blockIdx.x << 6) + (threadIdx.x & 63);
    int gx = (blockIdx.y << 2) + (threadIdx.x >> 6);
    int cz = blockIdx.z;                 // b*256 + c
    if (gy >= GYd) return;
    const unsigned* p = pooled + (size_t)cz*GXY;
    unsigned m = 0;
#pragma unroll
    for (int dx = -1; dx <= 1; dx++){
        int xx = gx + dx;
        if ((unsigned)xx >= GXd) continue;
#pragma unroll
        for (int dy = -1; dy <= 1; dy++){
            int yy = gy + dy;
            if ((unsigned)yy >= GYd) continue;
            unsigned u = p[(size_t)xx*GYd + yy];
            unsigned v = u ? u : 0x80000000u;   // empty -> mapped(0.0)
            m = m > v ? m : v;
        }
    }
    int b = cz >> 8, c = cz & 255;
    out[(((size_t)b*258 + c)*GXd + gx)*GYd + gy] = unmapf(m);
}

// ---------- residual channels (no pool) ----------
__global__ __launch_bounds__(256)
void k_res(const unsigned* __restrict__ pres, float* __restrict__ out){
    int idx = blockIdx.x*256 + threadIdx.x;
    const int total = NBd*2*GXY;
    if (idx >= total) return;
    int gy = idx % GYd;
    int t  = idx / GYd;
    int gx = t % GXd;  t /= GXd;
    int r  = t & 1;
    int b  = t >> 1;
    unsigned u = pres[idx];
    float f = u ? unmapf(u) : 0.f;
    out[(((size_t)b*258 + 256 + r)*GXd + gx)*GYd + gy] = f;
}

extern "C" void kernel_launch(void* const* d_in, const int* in_sizes, int n_in,
                              void* d_out, int out_size, void* d_ws, size_t ws_size,
                              hipStream_t stream){
    (void)n_in; (void)out_size; (void)ws_size;
    const float* fea   = (const float*)d_in[0];
    const int*   ind   = (const int*)  d_in[1];
    const float* bn0_g = (const float*)d_in[2];
    const float* bn0_b = (const float*)d_in[3];
    const float* w1    = (const float*)d_in[4];
    const float* b1    = (const float*)d_in[5];
    const float* bn1_g = (const float*)d_in[6];
    const float* bn1_b = (const float*)d_in[7];
    const float* w2    = (const float*)d_in[8];
    const float* b2    = (const float*)d_in[9];
    const float* bn2_g = (const float*)d_in[10];
    const float* bn2_b = (const float*)d_in[11];
    const float* w3    = (const float*)d_in[12];
    const float* b3    = (const float*)d_in[13];
    const float* bn3_g = (const float*)d_in[14];
    const float* bn3_b = (const float*)d_in[15];
    const float* w4    = (const float*)d_in[16];
    const float* b4    = (const float*)d_in[17];

    int n = in_sizes[0] / 11;
    float invN = 1.0f / (float)n;

    unsigned* pooled = (unsigned*)d_ws;
    unsigned* pres   = pooled + (size_t)NBd*256*GXY;
    float* stats = (float*)(pres + (size_t)NBd*2*GXY);
    float* sum0 = stats;       float* sq0 = stats + 16;
    float* sum1 = stats + 32;  float* sq1 = stats + 64;
    float* sum2 = stats + 96;  float* sq2 = stats + 160;
    float* sum3 = stats + 224; float* sq3 = stats + 352;
    float* a0 = stats + 480;   float* c0 = stats + 496;
    float* a1 = stats + 512;   float* c1 = stats + 544;
    float* a2 = stats + 576;   float* c2 = stats + 640;
    float* a3 = stats + 704;   float* c3 = stats + 832;

    size_t total_bytes = (size_t)((char*)(stats + 960) - (char*)d_ws);
    hipMemsetAsync(d_ws, 0, total_bytes, stream);

    int nb = (n + 255) / 256;
    k_stats0<<<nb, 256, 0, stream>>>(fea, sum0, sq0, n);
    k_fin<<<1, 128, 0, stream>>>(sum0, sq0, bn0_g, bn0_b, a0, c0, 9,  invN);
    k_stats1<<<nb, 256, 0, stream>>>(fea, w1, b1, a0, c0, sum1, sq1, n);
    k_fin<<<1, 128, 0, stream>>>(sum1, sq1, bn1_g, bn1_b, a1, c1, 32, invN);
    k_stats2<<<nb, 256, 0, stream>>>(fea, w1, b1, w2, b2, a0, c0, a1, c1, sum2, sq2, n);
    k_fin<<<1, 128, 0, stream>>>(sum2, sq2, bn2_g, bn2_b, a2, c2, 64, invN);
    k_stats3<<<nb, 256, 0, stream>>>(fea, w1, b1, w2, b2, w3, b3,
                                     a0, c0, a1, c1, a2, c2, sum3, sq3, n);
    k_fin<<<1, 128, 0, stream>>>(sum3, sq3, bn3_g, bn3_b, a3, c3, 128, invN);

    k_scatter<<<nb, 256, 0, stream>>>(fea, ind, w1, b1, w2, b2, w3, b3, w4, b4,
                                      a0, c0, a1, c1, a2, c2, a3, c3,
                                      pooled, pres, n);

    k_maxpool<<<dim3(6, 120, 512), 256, 0, stream>>>(pooled, (float*)d_out);
    k_res<<<(NBd*2*GXY + 255) / 256, 256, 0, stream>>>(pres, (float*)d_out);
}

// Round 2
// 21899.152 us; speedup vs baseline: 1.0998x; 1.0998x over previous
//
#include <hip/hip_runtime.h>
#include <cstdint>
#include <cstddef>

#define GXd 480
#define GYd 360
#define NBd 2
#define GXY (480*360)
#define EPSBN 1e-5f

// ---------- order-preserving float <-> uint map (for atomic max) ----------
__device__ __forceinline__ unsigned mapf(float f){
    unsigned u = __float_as_uint(f);
    return (u & 0x80000000u) ? ~u : (u | 0x80000000u);
}
__device__ __forceinline__ float unmapf(unsigned m){
    return (m & 0x80000000u) ? __uint_as_float(m ^ 0x80000000u)
                             : __uint_as_float(~m);
}

// ---------- bf16 helpers (RTN-even) ----------
__device__ __forceinline__ unsigned short f2bf(float f){
    unsigned u = __float_as_uint(f);
    unsigned r = (u + 0x7FFFu + ((u >> 16) & 1u)) >> 16;
    return (unsigned short)r;
}
__device__ __forceinline__ float bf2f(unsigned short s){
    return __uint_as_float(((unsigned)s) << 16);
}

// ---------- dense layer helper (fully unrolled, register-resident) ----------
template<int DIN, int DOUT>
__device__ __forceinline__ void dense(const float (&in)[DIN], float (&out)[DOUT],
                                      const float* __restrict__ w,
                                      const float* __restrict__ b){
#pragma unroll
    for (int j = 0; j < DOUT; j++) out[j] = b[j];
#pragma unroll
    for (int d = 0; d < DIN; d++){
        float v = in[d];
#pragma unroll
        for (int j = 0; j < DOUT; j++) out[j] = fmaf(v, w[d*DOUT + j], out[j]);
    }
}

// ---------- block-level sum/sumsq reduction of a per-thread register array ----------
template<int D>
__device__ __forceinline__ void reduce_stats(const float (&h)[D], bool valid,
                                             float* __restrict__ gsum,
                                             float* __restrict__ gsq){
    __shared__ float ssum[D];
    __shared__ float ssq[D];
    int tid = threadIdx.x;
    for (int t = tid; t < D; t += 256){ ssum[t] = 0.f; ssq[t] = 0.f; }
    __syncthreads();
#pragma unroll
    for (int j = 0; j < D; j++){
        float v = valid ? h[j] : 0.f;
        float s = v * v;
#pragma unroll
        for (int o = 32; o > 0; o >>= 1){
            v += __shfl_down(v, o, 64);
            s += __shfl_down(s, o, 64);
        }
        if ((tid & 63) == 0){
            atomicAdd(&ssum[j], v);
            atomicAdd(&ssq[j], s);
        }
    }
    __syncthreads();
    for (int t = tid; t < D; t += 256){
        atomicAdd(&gsum[t], ssum[t]);
        atomicAdd(&gsq[t], ssq[t]);
    }
}

// ---------- stats of raw input columns 0..8 ----------
__global__ __launch_bounds__(256)
void k_stats0(const float* __restrict__ fea, float* gsum, float* gsq, int n){
    int i = blockIdx.x*256 + threadIdx.x;
    bool valid = i < n;
    int i2 = valid ? i : 0;
    float x[9];
#pragma unroll
    for (int d = 0; d < 9; d++) x[d] = fea[(size_t)i2*11 + d];
    reduce_stats<9>(x, valid, gsum, gsq);
}

// ---------- finalize BN: a = g*rsqrt(var+eps); c = b - mu*a ----------
__global__ void k_fin(const float* __restrict__ sum, const float* __restrict__ sq,
                      const float* __restrict__ g, const float* __restrict__ bb,
                      float* __restrict__ a_out, float* __restrict__ c_out,
                      int D, float invN){
    int t = threadIdx.x;
    if (t < D){
        float mu  = sum[t] * invN;
        float var = fmaf(-mu, mu, sq[t] * invN);
        float rs  = rsqrtf(var + EPSBN);
        float a   = rs * g[t];
        a_out[t] = a;
        c_out[t] = fmaf(-mu, a, bb[t]);
    }
}

// ---------- layer1: bn0 -> 9x32 dense; write z1; stats(z1); res atomics ----------
__global__ __launch_bounds__(256)
void k_l1(const float* __restrict__ fea, const int* __restrict__ ind,
          const float* __restrict__ w1, const float* __restrict__ b1,
          const float* __restrict__ a0, const float* __restrict__ c0,
          float* __restrict__ z1, unsigned* __restrict__ pres,
          float* gsum, float* gsq, int n){
    int i = blockIdx.x*256 + threadIdx.x;
    bool valid = i < n;
    int i2 = valid ? i : 0;
    float x[9];
#pragma unroll
    for (int d = 0; d < 9; d++) x[d] = fmaf(fea[(size_t)i2*11 + d], a0[d], c0[d]);
    float h[32];
    dense<9,32>(x, h, w1, b1);
    if (valid){
        float4* dst = (float4*)(z1 + (size_t)i*32);
#pragma unroll
        for (int q = 0; q < 8; q++)
            dst[q] = make_float4(h[q*4], h[q*4+1], h[q*4+2], h[q*4+3]);
        float r0 = fea[(size_t)i*11 + 9];
        float r1 = fea[(size_t)i*11 + 10];
        int bb = ind[(size_t)i*3 + 0];
        int gx = ind[(size_t)i*3 + 1];
        int gy = ind[(size_t)i*3 + 2];
        size_t rbase = (size_t)bb*2*GXY + (size_t)gx*GYd + gy;
        atomicMax(pres + rbase,       mapf(r0));
        atomicMax(pres + rbase + GXY, mapf(r1));
    }
    reduce_stats<32>(h, valid, gsum, gsq);
}

// ---------- layer2: bn1relu(z1) @ w2 (LDS); write z2; stats(z2) ----------
__global__ __launch_bounds__(256)
void k_l2(const float* __restrict__ z1,
          const float* __restrict__ w2, const float* __restrict__ b2,
          const float* __restrict__ a1, const float* __restrict__ c1,
          float* __restrict__ z2, float* gsum, float* gsq, int n){
    __shared__ float4 w2s[32*16];            // [k][j4], 32x64 floats
    for (int e = threadIdx.x; e < 2048; e += 256) ((float*)w2s)[e] = w2[e];
    __syncthreads();
    int i = blockIdx.x*256 + threadIdx.x;
    bool valid = i < n;
    int i2 = valid ? i : 0;
    float h[32];
    const float4* src = (const float4*)(z1 + (size_t)i2*32);
#pragma unroll
    for (int q = 0; q < 8; q++){
        float4 v = src[q];
        h[q*4+0] = fmaxf(fmaf(v.x, a1[q*4+0], c1[q*4+0]), 0.f);
        h[q*4+1] = fmaxf(fmaf(v.y, a1[q*4+1], c1[q*4+1]), 0.f);
        h[q*4+2] = fmaxf(fmaf(v.z, a1[q*4+2], c1[q*4+2]), 0.f);
        h[q*4+3] = fmaxf(fmaf(v.w, a1[q*4+3], c1[q*4+3]), 0.f);
    }
    float acc[64];
#pragma unroll
    for (int j = 0; j < 64; j++) acc[j] = b2[j];
#pragma unroll
    for (int k = 0; k < 32; k++){
        float v = h[k];
#pragma unroll
        for (int q = 0; q < 16; q++){
            float4 w = w2s[k*16 + q];
            acc[q*4+0] = fmaf(v, w.x, acc[q*4+0]);
            acc[q*4+1] = fmaf(v, w.y, acc[q*4+1]);
            acc[q*4+2] = fmaf(v, w.z, acc[q*4+2]);
            acc[q*4+3] = fmaf(v, w.w, acc[q*4+3]);
        }
    }
    if (valid){
        float4* dst = (float4*)(z2 + (size_t)i*64);
#pragma unroll
        for (int q = 0; q < 16; q++)
            dst[q] = make_float4(acc[q*4], acc[q*4+1], acc[q*4+2], acc[q*4+3]);
    }
    reduce_stats<64>(acc, valid, gsum, gsq);
}

// ---------- layer3: bn2relu(z2) @ w3 (LDS); write z3 (bf16); stats(rounded z3) ----------
__global__ __launch_bounds__(256)
void k_l3(const float* __restrict__ z2,
          const float* __restrict__ w3, const float* __restrict__ b3,
          const float* __restrict__ a2, const float* __restrict__ c2,
          unsigned short* __restrict__ z3, float* gsum, float* gsq, int n){
    __shared__ float4 w3s[64*32];            // [k][j4], 64x128 floats = 32 KB
    for (int e = threadIdx.x; e < 8192; e += 256) ((float*)w3s)[e] = w3[e];
    __syncthreads();
    int i = blockIdx.x*256 + threadIdx.x;
    bool valid = i < n;
    int i2 = valid ? i : 0;
    float h[64];
    const float4* src = (const float4*)(z2 + (size_t)i2*64);
#pragma unroll
    for (int q = 0; q < 16; q++){
        float4 v = src[q];
        h[q*4+0] = fmaxf(fmaf(v.x, a2[q*4+0], c2[q*4+0]), 0.f);
        h[q*4+1] = fmaxf(fmaf(v.y, a2[q*4+1], c2[q*4+1]), 0.f);
        h[q*4+2] = fmaxf(fmaf(v.z, a2[q*4+2], c2[q*4+2]), 0.f);
        h[q*4+3] = fmaxf(fmaf(v.w, a2[q*4+3], c2[q*4+3]), 0.f);
    }
    for (int cb = 0; cb < 128; cb += 32){
        float acc[32];
#pragma unroll
        for (int cc = 0; cc < 32; cc++) acc[cc] = b3[cb + cc];
#pragma unroll
        for (int k = 0; k < 64; k++){
            float v = h[k];
#pragma unroll
            for (int q = 0; q < 8; q++){
                float4 w = w3s[k*32 + (cb >> 2) + q];
                acc[q*4+0] = fmaf(v, w.x, acc[q*4+0]);
                acc[q*4+1] = fmaf(v, w.y, acc[q*4+1]);
                acc[q*4+2] = fmaf(v, w.z, acc[q*4+2]);
                acc[q*4+3] = fmaf(v, w.w, acc[q*4+3]);
            }
        }
        // round to bf16; stats from the ROUNDED values so bn3 exactly matches what l4 reads
        float rv[32];
        unsigned ob[16];
#pragma unroll
        for (int m = 0; m < 16; m++){
            unsigned short lo = f2bf(acc[2*m]);
            unsigned short hi = f2bf(acc[2*m+1]);
            ob[m] = (unsigned)lo | ((unsigned)hi << 16);
            rv[2*m]   = bf2f(lo);
            rv[2*m+1] = bf2f(hi);
        }
        if (valid){
            uint4* dst = (uint4*)(z3 + (size_t)i*128 + cb);
#pragma unroll
            for (int q = 0; q < 4; q++)
                dst[q] = make_uint4(ob[q*4], ob[q*4+1], ob[q*4+2], ob[q*4+3]);
        }
        reduce_stats<32>(rv, valid, gsum + cb, gsq + cb);
    }
}

// ---------- layer4 + scatter: bn3relu(z3) @ w4-slice (LDS) -> atomicMax channel-last grid ----------
__global__ __launch_bounds__(256)
void k_l4(const unsigned short* __restrict__ z3, const int* __restrict__ ind,
          const float* __restrict__ w4, const float* __restrict__ b4,
          const float* __restrict__ a3, const float* __restrict__ c3,
          unsigned* __restrict__ pooled, int n){
    __shared__ float4 w4s[128*8];            // [k][c4], 128x32 floats = 16 KB
    int c0 = blockIdx.y * 32;
    for (int e = threadIdx.x; e < 4096; e += 256){
        int k = e >> 5, cc = e & 31;
        ((float*)w4s)[e] = w4[k*256 + c0 + cc];
    }
    __syncthreads();
    int t = threadIdx.x;
    int i0 = blockIdx.x*512 + t;
    int i1 = i0 + 256;
    bool v0 = i0 < n, v1 = i1 < n;
    int j0 = v0 ? i0 : 0, j1 = v1 ? i1 : 0;
    float acc0[32], acc1[32];
#pragma unroll
    for (int cc = 0; cc < 32; cc++){ float bv = b4[c0 + cc]; acc0[cc] = bv; acc1[cc] = bv; }
    const uint4* r0p = (const uint4*)(z3 + (size_t)j0*128);
    const uint4* r1p = (const uint4*)(z3 + (size_t)j1*128);
#pragma unroll
    for (int kb = 0; kb < 8; kb++){          // k-chunks of 16
        uint4 ua = r0p[kb*2], ub = r0p[kb*2+1];
        uint4 uc = r1p[kb*2], ud = r1p[kb*2+1];
        unsigned u0[8] = {ua.x, ua.y, ua.z, ua.w, ub.x, ub.y, ub.z, ub.w};
        unsigned u1[8] = {uc.x, uc.y, uc.z, uc.w, ud.x, ud.y, ud.z, ud.w};
        float h0[16], h1[16];
#pragma unroll
        for (int m = 0; m < 8; m++){
            int k = kb*16 + 2*m;
            float aL = a3[k], cL = c3[k], aH = a3[k+1], cH = c3[k+1];
            h0[2*m]   = fmaxf(fmaf(__uint_as_float(u0[m] << 16),          aL, cL), 0.f);
            h0[2*m+1] = fmaxf(fmaf(__uint_as_float(u0[m] & 0xFFFF0000u), aH, cH), 0.f);
            h1[2*m]   = fmaxf(fmaf(__uint_as_float(u1[m] << 16),          aL, cL), 0.f);
            h1[2*m+1] = fmaxf(fmaf(__uint_as_float(u1[m] & 0xFFFF0000u), aH, cH), 0.f);
        }
#pragma unroll
        for (int kk = 0; kk < 16; kk++){
            float va = h0[kk], vb = h1[kk];
#pragma unroll
            for (int q = 0; q < 8; q++){
                float4 w = w4s[(kb*16 + kk)*8 + q];
                acc0[q*4+0] = fmaf(va, w.x, acc0[q*4+0]);
                acc0[q*4+1] = fmaf(va, w.y, acc0[q*4+1]);
                acc0[q*4+2] = fmaf(va, w.z, acc0[q*4+2]);
                acc0[q*4+3] = fmaf(va, w.w, acc0[q*4+3]);
                acc1[q*4+0] = fmaf(vb, w.x, acc1[q*4+0]);
                acc1[q*4+1] = fmaf(vb, w.y, acc1[q*4+1]);
                acc1[q*4+2] = fmaf(vb, w.z, acc1[q*4+2]);
                acc1[q*4+3] = fmaf(vb, w.w, acc1[q*4+3]);
            }
        }
    }
    if (v0){
        int bb = ind[(size_t)i0*3], gx = ind[(size_t)i0*3+1], gy = ind[(size_t)i0*3+2];
        unsigned* p = pooled + ((((size_t)bb*GXd + gx)*GYd + gy)*256 + c0);
#pragma unroll
        for (int cc = 0; cc < 32; cc++) atomicMax(p + cc, mapf(acc0[cc]));
    }
    if (v1){
        int bb = ind[(size_t)i1*3], gx = ind[(size_t)i1*3+1], gy = ind[(size_t)i1*3+2];
        unsigned* p = pooled + ((((size_t)bb*GXd + gx)*GYd + gy)*256 + c0);
#pragma unroll
        for (int cc = 0; cc < 32; cc++) atomicMax(p + cc, mapf(acc1[cc]));
    }
}

// ---------- 3x3 maxpool: channel-last input, planar output ----------
__global__ __launch_bounds__(256)
void k_maxpool(const unsigned* __restrict__ pooled, float* __restrict__ out){
    int c  = threadIdx.x;
    int gy0 = blockIdx.x * 32;
    int gx0 = blockIdx.y * 4;
    int b   = blockIdx.z;
    const unsigned* base = pooled + (size_t)b*GXY*256 + c;
    float* obase = out + ((size_t)b*258 + c)*GXY;
    unsigned cmA[4], cmB[4];
#pragma unroll
    for (int g = 0; g < 4; g++){ cmA[g] = 0; cmB[g] = 0; }
    for (int tt = 0; tt < 34; tt++){
        int yy = gy0 - 1 + tt;
        bool yok = (unsigned)yy < (unsigned)GYd;
        unsigned v[6];
#pragma unroll
        for (int r = 0; r < 6; r++){
            int xx = gx0 - 1 + r;
            unsigned u = 0;
            if (yok && (unsigned)xx < (unsigned)GXd){
                unsigned raw = base[((size_t)xx*GYd + yy)*256];
                u = raw ? raw : 0x80000000u;     // empty -> mapped(0.0)
            }
            v[r] = u;
        }
        unsigned cm[4];
#pragma unroll
        for (int g = 0; g < 4; g++){
            unsigned m = v[g] > v[g+1] ? v[g] : v[g+1];
            cm[g] = m > v[g+2] ? m : v[g+2];
        }
        if (tt >= 2){
            int oy = yy - 1;
            if (oy < gy0 + 32 && oy < GYd){
#pragma unroll
                for (int g = 0; g < 4; g++){
                    unsigned m = cmA[g] > cmB[g] ? cmA[g] : cmB[g];
                    m = m > cm[g] ? m : cm[g];
                    obase[(size_t)(gx0+g)*GYd + oy] = unmapf(m);
                }
            }
        }
#pragma unroll
        for (int g = 0; g < 4; g++){ cmA[g] = cmB[g]; cmB[g] = cm[g]; }
    }
}

// ---------- residual channels (no pool) ----------
__global__ __launch_bounds__(256)
void k_res(const unsigned* __restrict__ pres, float* __restrict__ out){
    int idx = blockIdx.x*256 + threadIdx.x;
    const int total = NBd*2*GXY;
    if (idx >= total) return;
    int gy = idx % GYd;
    int t  = idx / GYd;
    int gx = t % GXd;  t /= GXd;
    int r  = t & 1;
    int b  = t >> 1;
    unsigned u = pres[idx];
    float f = u ? unmapf(u) : 0.f;
    out[(((size_t)b*258 + 256 + r)*GXd + gx)*GYd + gy] = f;
}

extern "C" void kernel_launch(void* const* d_in, const int* in_sizes, int n_in,
                              void* d_out, int out_size, void* d_ws, size_t ws_size,
                              hipStream_t stream){
    (void)n_in; (void)out_size; (void)ws_size;
    const float* fea   = (const float*)d_in[0];
    const int*   ind   = (const int*)  d_in[1];
    const float* bn0_g = (const float*)d_in[2];
    const float* bn0_b = (const float*)d_in[3];
    const float* w1    = (const float*)d_in[4];
    const float* b1    = (const float*)d_in[5];
    const float* bn1_g = (const float*)d_in[6];
    const float* bn1_b = (const float*)d_in[7];
    const float* w2    = (const float*)d_in[8];
    const float* b2    = (const float*)d_in[9];
    const float* bn2_g = (const float*)d_in[10];
    const float* bn2_b = (const float*)d_in[11];
    const float* w3    = (const float*)d_in[12];
    const float* b3    = (const float*)d_in[13];
    const float* bn3_g = (const float*)d_in[14];
    const float* bn3_b = (const float*)d_in[15];
    const float* w4    = (const float*)d_in[16];
    const float* b4    = (const float*)d_in[17];

    int n = in_sizes[0] / 11;
    float invN = 1.0f / (float)n;

    // ---- ws layout (with aliasing) ----
    const size_t PBYTES   = (size_t)NBd*256*GXY*4;          // 353,894,400
    const size_t Z3_OFF   = PBYTES;                         // bf16 z3: 61,440,000 B
    const size_t PRES_OFF = Z3_OFF + (size_t)240000*128*2;  // 415,334,400
    const size_t STAT_OFF = PRES_OFF + (size_t)NBd*2*GXY*4; // 418,099,200

    unsigned* pooled = (unsigned*)d_ws;
    float*    z1     = (float*)d_ws;                              // aliases pooled[0 .. 30.7MB)
    float*    z2     = (float*)((char*)d_ws + 30720000);          // aliases pooled[30.7 .. 92.2MB)
    unsigned short* z3 = (unsigned short*)((char*)d_ws + Z3_OFF);
    unsigned* pres   = (unsigned*)((char*)d_ws + PRES_OFF);
    float*    stats  = (float*)((char*)d_ws + STAT_OFF);

    float* sum0 = stats;       float* sq0 = stats + 16;
    float* sum1 = stats + 32;  float* sq1 = stats + 64;
    float* sum2 = stats + 96;  float* sq2 = stats + 160;
    float* sum3 = stats + 224; float* sq3 = stats + 352;
    float* a0 = stats + 480;   float* c0 = stats + 496;
    float* a1 = stats + 512;   float* c1 = stats + 544;
    float* a2 = stats + 576;   float* c2 = stats + 640;
    float* a3 = stats + 704;   float* c3 = stats + 832;

    // zero pres + stats (small); pooled memset deferred until z1/z2 are dead
    hipMemsetAsync((char*)d_ws + PRES_OFF, 0, (size_t)NBd*2*GXY*4 + 960*4, stream);

    int nb = (n + 255) / 256;
    k_stats0<<<nb, 256, 0, stream>>>(fea, sum0, sq0, n);
    k_fin<<<1, 128, 0, stream>>>(sum0, sq0, bn0_g, bn0_b, a0, c0, 9,  invN);
    k_l1<<<nb, 256, 0, stream>>>(fea, ind, w1, b1, a0, c0, z1, pres, sum1, sq1, n);
    k_fin<<<1, 128, 0, stream>>>(sum1, sq1, bn1_g, bn1_b, a1, c1, 32, invN);
    k_l2<<<nb, 256, 0, stream>>>(z1, w2, b2, a1, c1, z2, sum2, sq2, n);
    k_fin<<<1, 128, 0, stream>>>(sum2, sq2, bn2_g, bn2_b, a2, c2, 64, invN);
    k_l3<<<nb, 256, 0, stream>>>(z2, w3, b3, a2, c2, z3, sum3, sq3, n);
    k_fin<<<1, 128, 0, stream>>>(sum3, sq3, bn3_g, bn3_b, a3, c3, 128, invN);

    // z1/z2 now dead -> zero the pooled grid they aliased
    hipMemsetAsync(d_ws, 0, PBYTES, stream);

    k_l4<<<dim3((n + 511) / 512, 8), 256, 0, stream>>>(z3, ind, w4, b4, a3, c3, pooled, n);

    k_maxpool<<<dim3(12, 120, 2), 256, 0, stream>>>(pooled, (float*)d_out);
    k_res<<<(NBd*2*GXY + 255) / 256, 256, 0, stream>>>(pres, (float*)d_out);
}